// Round 6
// baseline (124.636 us; speedup 1.0000x reference)
//
#include <hip/hip_runtime.h>

// Problem constants (fixed by the reference module)
#define B_ 16
#define L_ 2048
#define D_ 128
#define GROUP_ 16
#define NG_ (L_ / GROUP_)   // 128
#define LOG2E_ 1.44269504088896340736f

// DPP-based butterfly add within each 16-lane row (full-rate VALU, no LDS).
template<int CTRL>
__device__ __forceinline__ float dpp_add(float v) {
    int x = __builtin_amdgcn_update_dpp(0, __float_as_int(v), CTRL, 0xF, 0xF, false);
    return v + __int_as_float(x);
}
__device__ __forceinline__ float row16_sum(float v) {
    v = dpp_add<0xB1>(v);   // quad_perm(1,0,3,2)  ~ xor 1
    v = dpp_add<0x4E>(v);   // quad_perm(2,3,0,1)  ~ xor 2
    v = dpp_add<0x141>(v);  // row_half_mirror     ~ xor 4
    v = dpp_add<0x140>(v);  // row_mirror          ~ xor 8
    return v;
}

// Batched reciprocal: r[k] = 1/d[k] for 8 values with ONE v_rcp.
__device__ __forceinline__ void rcp8(const float d[8], float r[8]) {
    float p[8];
    p[0] = d[0];
#pragma unroll
    for (int k = 1; k < 8; ++k) p[k] = p[k - 1] * d[k];
    float R = __builtin_amdgcn_rcpf(p[7]);
#pragma unroll
    for (int k = 7; k >= 1; --k) { r[k] = p[k - 1] * R; R *= d[k]; }
    r[0] = R;
}

// One block per (b,g) group. 256 threads = 16 rows x 16 lanes, 8 elems/thread.
//
// Round-5 evidence: dur is INSENSITIVE to inner-loop instruction mix
// (R2/R4/R5 all ~54us with 32/32/18 trans per thread-step) => the pin is
// the per-step __syncthreads rendezvous, not VALU issue. This version
// replaces the barrier with flag-gated producer->consumer handoff:
// 16 dedicated xj slots (no WAR reuse => no rendezvous), publisher sets
// a per-step flag after a release fence, consumers spin (broadcast read).
__global__ __launch_bounds__(256, 4) void ncn_kernel(
    const float* __restrict__ x,       // (B, L, D)
    const int*   __restrict__ gt,      // (B, L) permutation
    const int*   __restrict__ ctxlens, // (B,)
    const float* __restrict__ W,       // (2D,)
    const float* __restrict__ nalpha,  // (2,)
    const float* __restrict__ ngamma,  // (2D,)
    const float* __restrict__ nbeta,   // (2D,)
    float* __restrict__ out)           // (2, B, L, D) concat: yi_out, ya_out
{
    const int blk = blockIdx.x;
    const int b   = blk >> 7;      // / NG_
    const int g   = blk & (NG_ - 1);
    const int tid = threadIdx.x;
    const int row = tid >> 4;      // 0..15 (token within group)
    const int rl  = tid & 15;      // 0..15 (lane within row)
    const int d0  = rl << 3;       // 8 d-elements per thread

    __shared__ float s_xj[GROUP_][D_];   // one slot per step: no WAR hazard
    __shared__ int   s_flag[GROUP_];     // publish flags

    if (tid < GROUP_) s_flag[tid] = 0;

    const float a1 = nalpha[0];
    const float a2 = nalpha[1];
    const float ca = -a1 * LOG2E_;        // exp2 coefficient, path 1
    const float S  = -2.0f * a2 * LOG2E_; // za scale, path 2
    const bool  selMin = (S < 0.0f);      // leaky-relu under sign flip

    // Per-chunk constants in registers (reused 16x). Folded/pre-scaled forms.
    float Wi[8], Wj[8], G1S[8], B1S[8], G2[8], B2[8];
    {
        float g1r[8], b1r[8], g2r[8], b2r[8];
        *(float4*)&Wi[0]  = *(const float4*)(W + d0);
        *(float4*)&Wi[4]  = *(const float4*)(W + d0 + 4);
        *(float4*)&Wj[0]  = *(const float4*)(W + D_ + d0);
        *(float4*)&Wj[4]  = *(const float4*)(W + D_ + d0 + 4);
        *(float4*)&g1r[0] = *(const float4*)(ngamma + d0);
        *(float4*)&g1r[4] = *(const float4*)(ngamma + d0 + 4);
        *(float4*)&g2r[0] = *(const float4*)(ngamma + D_ + d0);
        *(float4*)&g2r[4] = *(const float4*)(ngamma + D_ + d0 + 4);
        *(float4*)&b1r[0] = *(const float4*)(nbeta + d0);
        *(float4*)&b1r[4] = *(const float4*)(nbeta + d0 + 4);
        *(float4*)&b2r[0] = *(const float4*)(nbeta + D_ + d0);
        *(float4*)&b2r[4] = *(const float4*)(nbeta + D_ + d0 + 4);
#pragma unroll
        for (int k = 0; k < 8; ++k) {
            G1S[k] = S * 2.0f * g1r[k];          // S*(2*g1)
            B1S[k] = S * (b1r[k] - g1r[k]);      // S*(b1-g1)
            G2[k]  = 2.0f * g2r[k];
            B2[k]  = b2r[k] - g2r[k];
        }
    }

    // Gather this row's token
    const int l   = g * GROUP_ + row;
    const int tok = gt[b * L_ + l];
    const float* xp = x + ((size_t)(b * L_ + tok)) * D_ + d0;

    float xi[8], za[8];
    *(float4*)&xi[0] = *(const float4*)xp;
    *(float4*)&xi[4] = *(const float4*)(xp + 4);
#pragma unroll
    for (int k = 0; k < 8; ++k) za[k] = 0.0f;

    __syncthreads();   // flags zeroed & visible (only block-wide barrier)

    volatile int* vflag = (volatile int*)s_flag;

    // Row 0 publishes slot 0 (its loaded xi)
    if (row == 0) {
        *(float4*)&s_xj[0][d0]     = *(float4*)&xi[0];
        *(float4*)&s_xj[0][d0 + 4] = *(float4*)&xi[4];
        __threadfence_block();          // data before flag
        if (rl == 0) vflag[0] = 1;
    }

    for (int j = 0; j < GROUP_; ++j) {
        // Wait until slot j is published (steady state: falls through).
        while (vflag[j] == 0) { __builtin_amdgcn_s_sleep(1); }

        float xjv[8];
        *(float4*)&xjv[0] = *(const float4*)&s_xj[j][d0];
        *(float4*)&xjv[4] = *(const float4*)&s_xj[j][d0 + 4];

        // sim = dot(xi,Wi) + dot(xj,Wj), combined, one 16-lane DPP reduce.
        float s = 0.0f;
#pragma unroll
        for (int k = 0; k < 8; ++k) s = fmaf(xi[k], Wi[k], s);
#pragma unroll
        for (int k = 0; k < 8; ++k) s = fmaf(xjv[k], Wj[k], s);
        s = row16_sum(s);
        const float cb = ca * s;   // ca * sim

        // Pass 1: sigmoid denominators for tanh(a1*T), batch rcp.
        float darr[8], r1[8];
#pragma unroll
        for (int k = 0; k < 8; ++k) {
            float u = fmaf(ca, xi[k], cb * xjv[k]);  // -2a1*log2e * T
            u = fminf(u, 15.0f);
            darr[k] = 1.0f + __builtin_amdgcn_exp2f(u);
        }
        rcp8(darr, r1);

        // Pass 2: scaled leaky-relu accumulate, path-2 denominators.
#pragma unroll
        for (int k = 0; k < 8; ++k) {
            float tnS = fmaf(G1S[k], r1[k], B1S[k]); // S*(g1*tanh+b1)
            float alt = 0.01f * tnS;
            float FvS = selMin ? fminf(tnS, alt) : fmaxf(tnS, alt);
            za[k] += FvS;                            // za = S * xa
            float z = fminf(za[k], 15.0f);
            darr[k] = 1.0f + __builtin_amdgcn_exp2f(z);
        }
        rcp8(darr, r1);

        // Pass 3: xi update
#pragma unroll
        for (int k = 0; k < 8; ++k)
            xi[k] += fmaf(G2[k], r1[k], B2[k]);

        // Publisher of step j+1 releases its slot as soon as it's ready.
        if (row == j + 1) {
            *(float4*)&s_xj[j + 1][d0]     = *(float4*)&xi[0];
            *(float4*)&s_xj[j + 1][d0 + 4] = *(float4*)&xi[4];
            __threadfence_block();      // data before flag
            if (rl == 0) vflag[j + 1] = 1;
        }
    }

    // Recover xa = za / S
    const float invS = 1.0f / S;
    float xa[8];
#pragma unroll
    for (int k = 0; k < 8; ++k) xa[k] = za[k] * invS;

    const bool valid = (g * GROUP_) < ctxlens[b];
    if (!valid) {
#pragma unroll
        for (int k = 0; k < 8; ++k) { xi[k] = 0.0f; xa[k] = 0.0f; }
    }

    // Scatter back through the permutation (bijective -> every out elem written)
    float* o1 = out + ((size_t)(b * L_ + tok)) * D_ + d0;
    float* o2 = o1 + (size_t)B_ * L_ * D_;
    *(float4*)o1       = *(float4*)&xi[0];
    *(float4*)(o1 + 4) = *(float4*)&xi[4];
    *(float4*)o2       = *(float4*)&xa[0];
    *(float4*)(o2 + 4) = *(float4*)&xa[4];
}

extern "C" void kernel_launch(void* const* d_in, const int* in_sizes, int n_in,
                              void* d_out, int out_size, void* d_ws, size_t ws_size,
                              hipStream_t stream) {
    const float* x  = (const float*)d_in[0];
    const int*   gt = (const int*)d_in[1];
    const int*   cl = (const int*)d_in[2];
    const float* W  = (const float*)d_in[3];
    const float* na = (const float*)d_in[4];
    const float* ng = (const float*)d_in[5];
    const float* nb = (const float*)d_in[6];
    float* out = (float*)d_out;

    ncn_kernel<<<B_ * NG_, 256, 0, stream>>>(x, gt, cl, W, na, ng, nb, out);
}